// Round 10
// baseline (212.721 us; speedup 1.0000x reference)
//
#include <hip/hip_runtime.h>

// SinePredictor:
//   s = h[edges[0]]; o = h[edges[1]]            [E,128] fp32 gathers
//   score = sin(s-o) @ W.T + b                  [E,1]  (bias cancels in softmax)
//   score = softmax over consecutive pairs      [E/2,2] -> [E,1]
//   out = concat(score, score > 0.5)            2*E floats
//
// Evidence ledger:
//   R2/R5/R6/R9 fp32 d_in: 90-97 us, FETCH ~303 MB, 3.15-3.5 TB/s across FOUR
//     different structures; VGPR never rose; queueing math -> saturated on
//     memory SERVICE RATE (655 MB logical L2 traffic), not latency. MLP arc dead.
//   R3/R4/R8 bf16-in-ws: ~162 us - ws random gathers ~0.9 TB/s (likely
//     uncached/fine-grained allocation). Compression arc dead.
// R10: cut DEMAND via locality. Edges are independent (pair coupling only in
//   softmax) -> two-phase:
//     k0-k3: count-sort edge ids by src>>5 (4096 buckets, 32 nodes = 16 KB of
//            rows, L1-sized) into ws; entries pack {src,obj,edge}.
//     k4:    waves process CONTIGUOUS sorted spans: s-row gathers become
//            L1/L2 hits (~half of all gather traffic), o-rows stay random;
//            writes per-edge logit x to ws.
//     k5:    streaming pair softmax + mask from xbuf.
//   Deterministic: scatter order varies across replays but xbuf[e]/out[e]
//   values don't. hist re-zeroed every call; order/xbuf/out fully rewritten.

constexpr int DIMS      = 128;
constexpr int NB        = 4096;   // buckets
constexpr int KEY_SHIFT = 5;      // 32 nodes/bucket -> 16 KB of rows

using u32 = unsigned int;

// ---------------- k0: zero histogram ----------------------------------------
__global__ __launch_bounds__(1024) void zero_hist_kernel(u32* __restrict__ hist) {
    const int t = blockIdx.x * blockDim.x + threadIdx.x;
    if (t < NB) hist[t] = 0u;
}

// ---------------- k1: histogram of src buckets -------------------------------
__global__ __launch_bounds__(256) void hist_kernel(
    const int* __restrict__ edges, int E, u32* __restrict__ hist)
{
    int i = blockIdx.x * blockDim.x + threadIdx.x;
    const int stride = gridDim.x * blockDim.x;
    for (; i < E; i += stride)
        atomicAdd(&hist[((u32)edges[i]) >> KEY_SHIFT], 1u);
}

// ---------------- k2: exclusive prefix sum (single block) --------------------
__global__ __launch_bounds__(1024) void prefix_kernel(
    const u32* __restrict__ hist, u32* __restrict__ cursor)
{
    __shared__ u32 sums[1024];
    const int t = threadIdx.x;
    const u32 h0 = hist[4*t+0], h1 = hist[4*t+1], h2 = hist[4*t+2], h3 = hist[4*t+3];
    const u32 s  = h0 + h1 + h2 + h3;
    sums[t] = s;
    __syncthreads();
    for (int d = 1; d < 1024; d <<= 1) {
        const u32 v = (t >= d) ? sums[t-d] : 0u;
        __syncthreads();
        sums[t] += v;
        __syncthreads();
    }
    const u32 excl = sums[t] - s;
    cursor[4*t+0] = excl;
    cursor[4*t+1] = excl + h0;
    cursor[4*t+2] = excl + h0 + h1;
    cursor[4*t+3] = excl + h0 + h1 + h2;
}

// ---------------- k3: scatter packed entries into sorted order ---------------
// entry.x = src | (e & 0x7FFF) << 17 ; entry.y = obj | (e >> 15) << 17
// (src,obj < 2^17; e < 2^20)
__global__ __launch_bounds__(256) void scatter_kernel(
    const int* __restrict__ edges, int E, u32* __restrict__ cursor,
    uint2* __restrict__ order)
{
    int i = blockIdx.x * blockDim.x + threadIdx.x;
    const int stride = gridDim.x * blockDim.x;
    for (; i < E; i += stride) {
        const u32 src = (u32)edges[i];
        const u32 obj = (u32)edges[E + i];
        const u32 pos = atomicAdd(&cursor[src >> KEY_SHIFT], 1u);
        order[pos] = make_uint2(src | ((u32)(i & 0x7FFF) << 17),
                                obj | ((u32)(i >> 15) << 17));
    }
}

// ---------------- k4: sorted edge scoring ------------------------------------
// Quarter-wave (16 lanes, 32 B/lane) per edge; wave owns a CONTIGUOUS span of
// the sorted order -> s-rows of its span live in L1 (16 KB bucket rows).
__global__ __launch_bounds__(256) void score_sorted_kernel(
    const float* __restrict__ h,
    const uint2* __restrict__ order,
    const float* __restrict__ W,
    float*       __restrict__ xbuf,
    int E)
{
    const int lane    = threadIdx.x & 63;
    const int sub     = lane & 15;
    const int quarter = lane >> 4;
    const int wave_id = blockIdx.x * (blockDim.x >> 6) + (threadIdx.x >> 6);
    const int n_waves = gridDim.x * (blockDim.x >> 6);
    const int span    = (E + n_waves - 1) / n_waves;
    const int start   = wave_id * span;
    const int end     = min(E, start + span);

    const float4 wl = reinterpret_cast<const float4*>(W)[sub * 2 + 0];
    const float4 wh = reinterpret_cast<const float4*>(W)[sub * 2 + 1];

    for (int ib = start; ib < end; ib += 4) {
        const int  i     = ib + quarter;
        const bool valid = i < end;
        const int  ic    = valid ? i : end - 1;

        const uint2 ent = order[ic];
        const u32 src = ent.x & 0x1FFFFu;
        const u32 obj = ent.y & 0x1FFFFu;
        const u32 e   = (ent.x >> 17) | ((ent.y >> 17) << 15);

        const float4* sr = reinterpret_cast<const float4*>(h + (size_t)src * DIMS);
        const float4* om = reinterpret_cast<const float4*>(h + (size_t)obj * DIMS);
        const float4 s0 = sr[sub * 2 + 0];
        const float4 s1 = sr[sub * 2 + 1];
        const float4 o0 = om[sub * 2 + 0];
        const float4 o1 = om[sub * 2 + 1];

        float x = __sinf(s0.x - o0.x) * wl.x + __sinf(s0.y - o0.y) * wl.y
                + __sinf(s0.z - o0.z) * wl.z + __sinf(s0.w - o0.w) * wl.w
                + __sinf(s1.x - o1.x) * wh.x + __sinf(s1.y - o1.y) * wh.y
                + __sinf(s1.z - o1.z) * wh.z + __sinf(s1.w - o1.w) * wh.w;

        #pragma unroll
        for (int m = 8; m >= 1; m >>= 1) x += __shfl_xor(x, m, 64);

        if (sub == 0 && valid) xbuf[e] = x;
    }
}

// ---------------- k5: streaming pair softmax + mask --------------------------
__global__ __launch_bounds__(256) void softmax_kernel(
    const float* __restrict__ xbuf, float* __restrict__ out, int E)
{
    const int NP = E >> 1;
    int p = blockIdx.x * blockDim.x + threadIdx.x;
    const int stride = gridDim.x * blockDim.x;
    for (; p < NP; p += stride) {
        const float2 x  = reinterpret_cast<const float2*>(xbuf)[p];
        const float  p0 = 1.0f / (1.0f + __expf(x.y - x.x));
        const float  p1 = 1.0f / (1.0f + __expf(x.x - x.y));
        reinterpret_cast<float2*>(out)[p]     = make_float2(p0, p1);
        reinterpret_cast<float2*>(out + E)[p] =
            make_float2(p0 > 0.5f ? 1.0f : 0.0f, p1 > 0.5f ? 1.0f : 0.0f);
    }
}

// ---------------- Fallback: R5 fp32 single kernel (90 us) --------------------
__global__ __launch_bounds__(256, 6) void sine_predictor_fp32_kernel(
    const float* __restrict__ h,
    const int*   __restrict__ edges,
    const float* __restrict__ W,
    const float* __restrict__ b,
    float*       __restrict__ out,
    int n_edges)
{
    const int lane    = threadIdx.x & 63;
    const int sub     = lane & 15;
    const int quarter = lane >> 4;
    const int wave_id = blockIdx.x * (blockDim.x >> 6) + (threadIdx.x >> 6);
    const int n_waves = gridDim.x * (blockDim.x >> 6);
    const int n_ch    = (n_edges + 3) >> 2;

    const float4 wl  = reinterpret_cast<const float4*>(W)[sub * 2 + 0];
    const float4 wh  = reinterpret_cast<const float4*>(W)[sub * 2 + 1];
    const float bias = b[0];

    for (int c = wave_id; c < n_ch; c += n_waves) {
        const int e  = 4 * c + quarter;
        const int ec = min(e, n_edges - 1);
        const int src = edges[ec];
        const int obj = edges[n_edges + ec];
        const float4* sr = reinterpret_cast<const float4*>(h + (size_t)src * DIMS);
        const float4* om = reinterpret_cast<const float4*>(h + (size_t)obj * DIMS);
        const float4 s0 = sr[sub * 2 + 0];
        const float4 s1 = sr[sub * 2 + 1];
        const float4 o0 = om[sub * 2 + 0];
        const float4 o1 = om[sub * 2 + 1];
        float x = __sinf(s0.x - o0.x) * wl.x + __sinf(s0.y - o0.y) * wl.y
                + __sinf(s0.z - o0.z) * wl.z + __sinf(s0.w - o0.w) * wl.w
                + __sinf(s1.x - o1.x) * wh.x + __sinf(s1.y - o1.y) * wh.y
                + __sinf(s1.z - o1.z) * wh.z + __sinf(s1.w - o1.w) * wh.w;
        #pragma unroll
        for (int m = 8; m >= 1; m >>= 1) x += __shfl_xor(x, m, 64);
        x += bias;
        const float other = __shfl_xor(x, 16, 64);
        const float p = 1.0f / (1.0f + __expf(other - x));
        if (sub == 0 && e < n_edges) {
            out[e]           = p;
            out[n_edges + e] = (p > 0.5f) ? 1.0f : 0.0f;
        }
    }
}

extern "C" void kernel_launch(void* const* d_in, const int* in_sizes, int n_in,
                              void* d_out, int out_size, void* d_ws, size_t ws_size,
                              hipStream_t stream) {
    const float* h     = (const float*)d_in[0];
    const int*   edges = (const int*)d_in[1];
    const float* W     = (const float*)d_in[2];
    const float* b     = (const float*)d_in[3];
    float*       out   = (float*)d_out;

    const int n_edges = in_sizes[1] / 2;        // edges is [2, E]
    const int n_nodes = in_sizes[0] / DIMS;

    // ws layout: hist[NB] | cursor[NB] | order[E] (uint2) | xbuf[E] (float)
    const size_t off_cursor = (size_t)NB * 4;
    const size_t off_order  = off_cursor + (size_t)NB * 4;
    const size_t off_xbuf   = off_order + (size_t)n_edges * 8;
    const size_t need       = off_xbuf + (size_t)n_edges * 4;

    if (ws_size >= need && n_nodes <= (NB << KEY_SHIFT) && (n_edges & 1) == 0) {
        u32*   hist   = (u32*)d_ws;
        u32*   cursor = (u32*)((char*)d_ws + off_cursor);
        uint2* order  = (uint2*)((char*)d_ws + off_order);
        float* xbuf   = (float*)((char*)d_ws + off_xbuf);

        zero_hist_kernel<<<(NB + 1023) / 1024, 1024, 0, stream>>>(hist);
        hist_kernel<<<1024, 256, 0, stream>>>(edges, n_edges, hist);
        prefix_kernel<<<1, 1024, 0, stream>>>(hist, cursor);
        scatter_kernel<<<1024, 256, 0, stream>>>(edges, n_edges, cursor, order);
        score_sorted_kernel<<<2048, 256, 0, stream>>>(h, order, W, xbuf, n_edges);
        softmax_kernel<<<512, 256, 0, stream>>>(xbuf, out, n_edges);
    } else {
        sine_predictor_fp32_kernel<<<1536, 256, 0, stream>>>(h, edges, W, b, out, n_edges);
    }
}

// Round 11
// 92.402 us; speedup vs baseline: 2.3021x; 2.3021x over previous
//
#include <hip/hip_runtime.h>

// SinePredictor — FINAL (revert to R5, the session's best: 90.0-90.9 us).
//
//   s = h[edges[0]]; o = h[edges[1]]            [E,128] fp32 gathers
//   score = sin(s-o) @ W.T + b                  [E,1]
//   score = softmax over consecutive pairs      [E/2,2] -> [E,1]
//   out = concat(score, score > 0.5)            2*E floats
//
// Final evidence ledger (why this is the roofline):
//   R2/R5/R6/R9/R10 fp32 structures: 87-97 us, 3.1-3.5 TB/s on 267-306 MB
//     of compulsory L2-miss traffic (random 1KB row pairs on 8 non-coherent
//     L2s). Five structures converge -> random-gather SERVICE-RATE bound.
//   MLP arc dead: VGPR never rose past 32; queueing is saturated (8192 waves
//     already provide >MSHR-capacity concurrency); per-wave MLP irrelevant.
//   Compression arc dead: d_ws gathers run 0.9 TB/s regardless of store type
//     (NT or cached) or access structure -> allocation-level, unfixable.
//   Locality arc dead: src-bucket sort reached the one-sided compulsory floor
//     (267 MB) yet score time ~= R5; o-side randomness is irreducible, and
//     binning overhead (atomics + ws scatter) costs more than it saves.
//   sin-factorization (sin(s-o)=<u(src),v(obj)>, u,v 256-dim) doubles
//     gathered bytes -> strictly worse.
//   Floor arithmetic: ~270 MB / 3.5 TB/s ~= 77 us; achieved 90 us.
//
// Structure: quarter-wave (16 lanes) per edge, 32 B/lane (2x dwordx4);
// 4 edges (2 pairs) per wave; shuffle-reduce in the quarter, pair softmax
// via xor-16 shuffle; (256,6) occupancy cap; 1536 blocks = exact residency.

constexpr int DIMS = 128;

__global__ __launch_bounds__(256, 6) void sine_predictor_kernel(
    const float* __restrict__ h,
    const int*   __restrict__ edges,   // [2, E] int32
    const float* __restrict__ W,       // [1, 128]
    const float* __restrict__ b,       // [1]
    float*       __restrict__ out,     // [2*E]: scores then mask
    int n_edges)
{
    const int lane    = threadIdx.x & 63;
    const int sub     = lane & 15;     // floats sub*8 .. sub*8+7 of the row
    const int quarter = lane >> 4;     // which of 4 consecutive edges
    const int wave_id = blockIdx.x * (blockDim.x >> 6) + (threadIdx.x >> 6);
    const int n_waves = gridDim.x * (blockDim.x >> 6);
    const int n_ch    = (n_edges + 3) >> 2;   // chunks of 4 edges (2 pairs)

    const float4 wl  = reinterpret_cast<const float4*>(W)[sub * 2 + 0];
    const float4 wh  = reinterpret_cast<const float4*>(W)[sub * 2 + 1];
    const float bias = b[0];

    for (int c = wave_id; c < n_ch; c += n_waves) {
        const int e  = 4 * c + quarter;
        const int ec = min(e, n_edges - 1);
        const int src = edges[ec];
        const int obj = edges[n_edges + ec];

        const float4* sr = reinterpret_cast<const float4*>(h + (size_t)src * DIMS);
        const float4* om = reinterpret_cast<const float4*>(h + (size_t)obj * DIMS);
        const float4 s0 = sr[sub * 2 + 0];
        const float4 s1 = sr[sub * 2 + 1];
        const float4 o0 = om[sub * 2 + 0];
        const float4 o1 = om[sub * 2 + 1];

        float x = __sinf(s0.x - o0.x) * wl.x + __sinf(s0.y - o0.y) * wl.y
                + __sinf(s0.z - o0.z) * wl.z + __sinf(s0.w - o0.w) * wl.w
                + __sinf(s1.x - o1.x) * wh.x + __sinf(s1.y - o1.y) * wh.y
                + __sinf(s1.z - o1.z) * wh.z + __sinf(s1.w - o1.w) * wh.w;

        // reduce within the 16-lane quarter
        #pragma unroll
        for (int m = 8; m >= 1; m >>= 1) x += __shfl_xor(x, m, 64);
        x += bias;

        // pair softmax: partner quarter via xor lane 16
        const float other = __shfl_xor(x, 16, 64);
        const float p = 1.0f / (1.0f + __expf(other - x));   // == softmax
        if (sub == 0 && e < n_edges) {
            out[e]           = p;
            out[n_edges + e] = (p > 0.5f) ? 1.0f : 0.0f;
        }
    }
}

extern "C" void kernel_launch(void* const* d_in, const int* in_sizes, int n_in,
                              void* d_out, int out_size, void* d_ws, size_t ws_size,
                              hipStream_t stream) {
    const float* h     = (const float*)d_in[0];
    const int*   edges = (const int*)d_in[1];
    const float* W     = (const float*)d_in[2];
    const float* b     = (const float*)d_in[3];
    float*       out   = (float*)d_out;

    const int n_edges = in_sizes[1] / 2;   // edges is [2, E]

    // (256,6): 6 waves/SIMD cap; 1536 blocks = 256 CU x 6 blocks = exact
    // residency, grid-stride covers the 160k chunks with no serialized tail.
    sine_predictor_kernel<<<1536, 256, 0, stream>>>(h, edges, W, b, out, n_edges);
}